// Round 10
// baseline (281.011 us; speedup 1.0000x reference)
//
#include <hip/hip_runtime.h>

namespace {

constexpr int Bc = 4;
constexpr int Cc = 256;
constexpr int Pc = 128;
constexpr int NcT = 3136;  // true spatial size 56*56
constexpr int Np = 3200;   // padded to 25*128
constexpr int Sc = 5;
constexpr int KSn = 5;     // split-K chunks for abt (3200 = 5*640)
constexpr int KCH = 640;
constexpr float EPSc = 1e-5f;

typedef __attribute__((ext_vector_type(8))) short bf16x8;
typedef __attribute__((ext_vector_type(4))) float f32x4;
typedef __attribute__((ext_vector_type(8))) unsigned short u16x8;
typedef __attribute__((ext_vector_type(4))) unsigned short u16x4;

__device__ inline float bf2f(unsigned short u) {
    return __uint_as_float(((unsigned)u) << 16);
}
__device__ inline unsigned short f2bf(float f) {
    unsigned u = __float_as_uint(f);
    return (unsigned short)((u + 0x7FFFu + ((u >> 16) & 1u)) >> 16);
}

struct GP {
    const unsigned short* A; int lda; long aB; long aSl;
    const unsigned short* Bw; int ldb; long bB; long bSl;
    const unsigned short* A2; int lda2; long aB2;
    const unsigned short* B2; int ldb2; long bB2;
    int K; int K2; int nsl; int kchunk;
    unsigned short* outSM; int ldsm; long smB; long smSlice;
    unsigned short* outCM; long cmB;
    float* ps; float* ps2;                 // BNSTAT out, or FUSEBN stats in
    const float* gammap; const float* betap;  // FUSEBN BN params
    const float* dinv;
    const unsigned short* oin;
    float* resid;
};

// ---------------------------------------------------------------------------
// MFMA GEMM: D[m][n] = sum over slices/loops of A[m][k]*B[n][k] (K-contig).
// Tile MT(m) x 128(n), 4 waves, K-step 64, double-buffered LDS via
// global_load_lds(16B), granule swizzle phys = g ^ (row&7).
// EPI: 0 none, 1 relu.  CMOUT: 0 none, 1 plain col-major, 2 col-major*dinv[m]
// SPLITK: z=ks*4+b, K range [ks*kchunk,+kchunk), out += ks*smSlice
// BNSTAT: 1 col sums->ps, 2 +sumsq->ps2.  FUSEBN: A = resid + BN(oin) with
// scale/shift computed IN-BLOCK from ps/ps2+gamma/beta (resid updated).
// XORM: row-major store to row (m0^128)+r.  DUALK: second loop over (A2,B2,K2).
// ---------------------------------------------------------------------------
template <int MT, int EPI, int CMOUT, bool SPLITK, int BNSTAT, bool FUSEBN,
          bool XORM, bool DUALK>
__global__ __launch_bounds__(256) void mgemm(GP p)
{
    constexpr int TBA = MT * 64 * 2;
    constexpr int TBB = 128 * 64 * 2;
    constexpr int BUF = TBA + TBB;
    constexpr int OTB = MT * 132 * 4;
    constexpr int LDSZ = (2 * BUF > OTB + 2048) ? 2 * BUF : (OTB + 2048);
    __shared__ __align__(16) char lds[LDSZ];
    __shared__ float bnscl[256], bnshl[256];   // FUSEBN scale/shift (persist)

    int b, kstart;
    long smOff;
    if (SPLITK) {
        b = blockIdx.z & 3;
        int ks = blockIdx.z >> 2;
        kstart = ks * p.kchunk;
        smOff = (long)ks * p.smSlice;
    } else {
        b = blockIdx.z; kstart = 0; smOff = 0;
    }
    const int n0 = blockIdx.x * 128;
    const int m0 = blockIdx.y * MT;
    const int tid = threadIdx.x;
    const int w = tid >> 6, l = tid & 63;

    const unsigned short* Ab = p.A + (size_t)b * p.aB + (size_t)m0 * p.lda;
    const unsigned short* Bb = p.Bw + (size_t)b * p.bB + (size_t)n0 * p.ldb;

    const int srow8 = tid >> 3;                  // 0..31
    const int sgran = tid & 7;
    const int sswz = (sgran ^ (srow8 & 7)) * 8;  // swizzled source granule
    constexpr int AR = MT / 32;                  // A staging rounds

    constexpr int WC = (MT == 128) ? 2 : 4;      // waves along n
    constexpr int NB = 128 / WC / 16;            // B frags per wave
    const int wr = w / WC, wc = w % WC;

    f32x4 acc[4][NB] = {};
    float fup[AR][8];

    if constexpr (FUSEBN) {
        // in-block BN finalize: reduce 100 partial groups for channel tid
        float a = 0.f, a2 = 0.f;
        for (int g = 0; g < 100; ++g) {
            a += p.ps[(size_t)g * 256 + tid];
            a2 += p.ps2[(size_t)g * 256 + tid];
        }
        const float inv = 1.f / (float)(Bc * NcT);
        float mean = a * inv;
        float var = a2 * inv - mean * mean;
        float sc = p.gammap[tid] * rsqrtf(var + EPSc);
        bnscl[tid] = sc;
        bnshl[tid] = p.betap[tid] - mean * sc;
        __syncthreads();
    }

    auto stage1 = [&](int buf, int sl, int k0) {
        char* base = lds + buf * BUF;
        const unsigned short* As = Ab + (size_t)sl * p.aSl + k0 + sswz;
#pragma unroll
        for (int j = 0; j < AR; ++j)
            __builtin_amdgcn_global_load_lds(
                (const __attribute__((address_space(1))) void*)
                    (As + (size_t)(j * 32 + srow8) * p.lda),
                (__attribute__((address_space(3))) void*)(base + j * 4096 + tid * 16),
                16, 0, 0);
        const unsigned short* Bs = Bb + (size_t)sl * p.bSl + k0 + sswz;
#pragma unroll
        for (int j = 0; j < 4; ++j)
            __builtin_amdgcn_global_load_lds(
                (const __attribute__((address_space(1))) void*)
                    (Bs + (size_t)(j * 32 + srow8) * p.ldb),
                (__attribute__((address_space(3))) void*)(base + TBA + j * 4096 + tid * 16),
                16, 0, 0);
    };

    auto stageB1 = [&](int buf, int k0) {
        char* base = lds + buf * BUF + TBA;
        const unsigned short* Bs = Bb + k0 + sswz;
#pragma unroll
        for (int j = 0; j < 4; ++j)
            __builtin_amdgcn_global_load_lds(
                (const __attribute__((address_space(1))) void*)
                    (Bs + (size_t)(j * 32 + srow8) * p.ldb),
                (__attribute__((address_space(3))) void*)(base + j * 4096 + tid * 16),
                16, 0, 0);
    };

    auto fbLoad = [&](int k0) {
        const float* scp = bnscl + k0 + sgran * 8;
        const float* shp = bnshl + k0 + sgran * 8;
        float4 s0 = *(const float4*)scp, s1 = *(const float4*)(scp + 4);
        float4 h0 = *(const float4*)shp, h1 = *(const float4*)(shp + 4);
#pragma unroll
        for (int j = 0; j < AR; ++j) {
            int row = j * 32 + srow8;
            int n = m0 + row;
            size_t off = ((size_t)b * Np + n) * 256 + k0 + sgran * 8;
            if (n < NcT) {
                u16x8 ov = *(const u16x8*)(p.oin + off);
                float4 r0 = *(const float4*)(p.resid + off);
                float4 r1 = *(const float4*)(p.resid + off + 4);
                fup[j][0] = r0.x + fmaf(bf2f(ov[0]), s0.x, h0.x);
                fup[j][1] = r0.y + fmaf(bf2f(ov[1]), s0.y, h0.y);
                fup[j][2] = r0.z + fmaf(bf2f(ov[2]), s0.z, h0.z);
                fup[j][3] = r0.w + fmaf(bf2f(ov[3]), s0.w, h0.w);
                fup[j][4] = r1.x + fmaf(bf2f(ov[4]), s1.x, h1.x);
                fup[j][5] = r1.y + fmaf(bf2f(ov[5]), s1.y, h1.y);
                fup[j][6] = r1.z + fmaf(bf2f(ov[6]), s1.z, h1.z);
                fup[j][7] = r1.w + fmaf(bf2f(ov[7]), s1.w, h1.w);
                float4 w0, w1;
                w0.x = fup[j][0]; w0.y = fup[j][1]; w0.z = fup[j][2]; w0.w = fup[j][3];
                w1.x = fup[j][4]; w1.y = fup[j][5]; w1.z = fup[j][6]; w1.w = fup[j][7];
                *(float4*)(p.resid + off) = w0;
                *(float4*)(p.resid + off + 4) = w1;
            } else {
#pragma unroll
                for (int i = 0; i < 8; ++i) fup[j][i] = 0.f;
            }
        }
    };
    auto fbWrite = [&](int buf) {
        char* base = lds + buf * BUF;
#pragma unroll
        for (int j = 0; j < AR; ++j) {
            int row = j * 32 + srow8;
            u16x8 hv;
#pragma unroll
            for (int i = 0; i < 8; ++i) hv[i] = f2bf(fup[j][i]);
            *(u16x8*)(base + row * 128 + ((sgran ^ (row & 7)) << 4)) = hv;
        }
    };

    auto compute = [&](int buf) {
        const char* base = lds + buf * BUF;
        const int lo = l & 15, gq = l >> 4;
#pragma unroll
        for (int kh = 0; kh < 2; ++kh) {
            const int lg = kh * 4 + gq;
            bf16x8 bf[NB];
#pragma unroll
            for (int c = 0; c < NB; ++c) {
                int brow = wc * (16 * NB) + c * 16 + lo;
                bf[c] = *(const bf16x8*)(base + TBA + brow * 128 +
                                         ((lg ^ (brow & 7)) << 4));
            }
#pragma unroll
            for (int r = 0; r < 4; ++r) {
                int arow = wr * 64 + r * 16 + lo;
                bf16x8 af = *(const bf16x8*)(base + arow * 128 +
                                             ((lg ^ (arow & 7)) << 4));
#pragma unroll
                for (int c = 0; c < NB; ++c)
                    acc[r][c] = __builtin_amdgcn_mfma_f32_16x16x32_bf16(
                        af, bf[c], acc[r][c], 0, 0, 0);
            }
        }
    };

    if constexpr (FUSEBN) {
        const int nst = p.K >> 6;    // nsl==1, no DUALK in this mode
        fbLoad(kstart);
        fbWrite(0);
        stageB1(0, kstart);
        __syncthreads();
        for (int s = 0; s < nst; ++s) {
            if (s + 1 < nst) {
                fbLoad(kstart + ((s + 1) << 6));
                stageB1((s + 1) & 1, kstart + ((s + 1) << 6));
            }
            compute(s & 1);
            if (s + 1 < nst) fbWrite((s + 1) & 1);
            __syncthreads();
        }
    } else {
        const int nsteps1 = (SPLITK ? p.kchunk : p.K) >> 6;
        const int spl2 = DUALK ? (p.K2 >> 6) : 0;
        const int tot = p.nsl * nsteps1 + spl2;

        // second-loop staging (only instantiated for DUALK)
        const unsigned short* Ab2 = DUALK ?
            (p.A2 + (size_t)b * p.aB2 + (size_t)m0 * p.lda2) : nullptr;
        const unsigned short* Bb2 = DUALK ?
            (p.B2 + (size_t)b * p.bB2 + (size_t)n0 * p.ldb2) : nullptr;
        auto stage2 = [&](int buf, int k0) {
            if constexpr (DUALK) {
                char* base = lds + buf * BUF;
                const unsigned short* As = Ab2 + k0 + sswz;
#pragma unroll
                for (int j = 0; j < AR; ++j)
                    __builtin_amdgcn_global_load_lds(
                        (const __attribute__((address_space(1))) void*)
                            (As + (size_t)(j * 32 + srow8) * p.lda2),
                        (__attribute__((address_space(3))) void*)(base + j * 4096 + tid * 16),
                        16, 0, 0);
                const unsigned short* Bs = Bb2 + k0 + sswz;
#pragma unroll
                for (int j = 0; j < 4; ++j)
                    __builtin_amdgcn_global_load_lds(
                        (const __attribute__((address_space(1))) void*)
                            (Bs + (size_t)(j * 32 + srow8) * p.ldb2),
                        (__attribute__((address_space(3))) void*)(base + TBA + j * 4096 + tid * 16),
                        16, 0, 0);
            }
        };

        stage1(0, 0, kstart);
        __syncthreads();
        int sl = 0, st = 1;
        if (st == nsteps1) { st = 0; sl = 1; }
        for (int gs = 0; gs < tot; ++gs) {
            if (gs + 1 < tot) {
                if (sl < p.nsl) stage1((gs + 1) & 1, sl, kstart + (st << 6));
                else            stage2((gs + 1) & 1, st << 6);
                ++st;
                int lim = (sl < p.nsl) ? nsteps1 : spl2;
                if (st == lim) { st = 0; ++sl; }
            }
            compute(gs & 1);
            __syncthreads();
        }
    }

    // stage accumulators to LDS f32 [MT][132]
    float* ot = (float*)lds;
    {
        const int lo = l & 15, gq = l >> 4;
#pragma unroll
        for (int r = 0; r < 4; ++r)
#pragma unroll
            for (int c = 0; c < NB; ++c)
#pragma unroll
                for (int j = 0; j < 4; ++j) {
                    float v = acc[r][c][j];
                    if (EPI == 1) v = fmaxf(v, 0.f);
                    ot[(wr * 64 + r * 16 + gq * 4 + j) * 132 +
                       wc * (16 * NB) + c * 16 + lo] = v;
                }
    }
    __syncthreads();

    {   // row-major store
        constexpr int TPR = 256 / MT;
        const int r = tid / TPR;
        const int c0 = (tid % TPR) * (MT / 2);
        const int m0s = XORM ? (m0 ^ 128) : m0;
        unsigned short* dst = p.outSM + (size_t)b * p.smB + smOff +
                              (size_t)(m0s + r) * p.ldsm + n0 + c0;
#pragma unroll
        for (int k = 0; k < MT / 16; ++k) {
            u16x8 o;
#pragma unroll
            for (int j = 0; j < 8; ++j) o[j] = f2bf(ot[r * 132 + c0 + 8 * k + j]);
            *(u16x8*)(dst + 8 * k) = o;
        }
    }

    if (CMOUT) {   // column-major store
        const int c = tid >> 1, r0 = (tid & 1) * (MT / 2);
        const float* dv = p.dinv + (size_t)b * Np + m0 + r0;
        unsigned short* dst = p.outCM + (size_t)b * p.cmB +
                              (size_t)(n0 + c) * Np + m0 + r0;
#pragma unroll
        for (int k = 0; k < MT / 16; ++k) {
            u16x8 o;
#pragma unroll
            for (int j = 0; j < 8; ++j) {
                float v = ot[(r0 + 8 * k + j) * 132 + c];
                if (CMOUT == 2) v *= dv[8 * k + j];
                o[j] = f2bf(v);
            }
            *(u16x8*)(dst + 8 * k) = o;
        }
    }

    if (BNSTAT) {
        float* p1 = (float*)(lds + OTB);
        float* p2 = p1 + 256;
        const int col = tid & 127, half = tid >> 7;
        float s = 0.f, s2 = 0.f;
#pragma unroll
        for (int i = 0; i < MT / 2; ++i) {
            float v = ot[(half * (MT / 2) + i) * 132 + col];
            s += v;
            if (BNSTAT == 2) s2 = fmaf(v, v, s2);
        }
        p1[half * 128 + col] = s;
        if (BNSTAT == 2) p2[half * 128 + col] = s2;
        __syncthreads();
        if (tid < 128) {
            float aa = p1[tid] + p1[128 + tid];
            size_t slot = ((size_t)b * gridDim.y + blockIdx.y) * 256 + n0 + tid;
            p.ps[slot] = aa;
            if (BNSTAT == 2) p.ps2[slot] = p2[tid] + p2[128 + tid];
        }
    }
}

// ---------------------------------------------------------------------------
// prep: weight f32->bf16 (544 items) + input transpose (800 items)
// ---------------------------------------------------------------------------
__global__ __launch_bounds__(256) void prep_k(
    const float* __restrict__ x, const float* __restrict__ Wt,
    const float* __restrict__ Wp, const float* __restrict__ Wg,
    const float* __restrict__ W1, const float* __restrict__ W2,
    unsigned short* __restrict__ Wcomb, unsigned short* __restrict__ Wgh,
    unsigned short* __restrict__ W1h, unsigned short* __restrict__ W2h,
    float* __restrict__ out_sm, unsigned short* __restrict__ outh)
{
    __shared__ float tb[64][65];
    int item = blockIdx.x;
    int t = threadIdx.x;
    if (item < 544) {
        size_t e = ((size_t)item * 256 + t) * 4;
        const float* src; unsigned short* dst;
        if (e < 32768)       { src = Wt + e;           dst = Wcomb + e; }
        else if (e < 65536)  { src = Wp + (e - 32768); dst = Wcomb + e; }
        else if (e < 229376) { size_t o = e - 65536;  src = Wg + o; dst = Wgh + o; }
        else if (e < 393216) { size_t o = e - 229376; src = W1 + o; dst = W1h + o; }
        else                 { size_t o = e - 393216; src = W2 + o; dst = W2h + o; }
        float4 v = *(const float4*)src;
        u16x4 t4;
        t4[0] = f2bf(v.x); t4[1] = f2bf(v.y); t4[2] = f2bf(v.z); t4[3] = f2bf(v.w);
        *(u16x4*)dst = t4;
        return;
    }
    int it = item - 544;
    int nx = it % 50, cy = (it / 50) % 4, b = it / 200;
    int c0 = cy * 64, n0 = nx * 64;
    const bool pad = (n0 >= NcT);
    if (!pad) {
        int ci = t >> 2, nb = (t & 3) * 16;
        const float* src = x + ((size_t)b * Cc + c0 + ci) * NcT + n0 + nb;
#pragma unroll
        for (int k = 0; k < 4; ++k) {
            float4 v = *(const float4*)(src + 4 * k);
            tb[ci][nb + 4 * k + 0] = v.x; tb[ci][nb + 4 * k + 1] = v.y;
            tb[ci][nb + 4 * k + 2] = v.z; tb[ci][nb + 4 * k + 3] = v.w;
        }
    }
    __syncthreads();
    int r = t >> 2, cb = (t & 3) * 16;
    size_t off = ((size_t)b * Np + n0 + r) * 256 + c0 + cb;
    float vv[16];
#pragma unroll
    for (int j = 0; j < 16; ++j) vv[j] = pad ? 0.f : tb[cb + j][r];
    float* dst = out_sm + off;
#pragma unroll
    for (int k = 0; k < 4; ++k) {
        float4 v; v.x = vv[4*k]; v.y = vv[4*k+1]; v.z = vv[4*k+2]; v.w = vv[4*k+3];
        *(float4*)(dst + 4 * k) = v;
    }
    u16x8 h1, h2;
#pragma unroll
    for (int j = 0; j < 8; ++j) { h1[j] = f2bf(vv[j]); h2[j] = f2bf(vv[8 + j]); }
    unsigned short* dh = outh + off;
    *(u16x8*)dh = h1;
    *(u16x8*)(dh + 8) = h2;
}

// dinv + Ud fused: dinv[b][i] = d>0 ? rsqrt(d) : 0; Ud[b][i][q] = 0.5*dinv*U
__global__ __launch_bounds__(256) void dinvud_k(
    const unsigned short* __restrict__ U, const float* __restrict__ rp,
    float* __restrict__ dinv, unsigned short* __restrict__ Ud)
{
    __shared__ float rsl[256];
    __shared__ float dl[256];
    int b = blockIdx.y, tid = threadIdx.x;
    float s = 0.f;
    for (int j = 0; j < 25; ++j) s += rp[((size_t)b * 25 + j) * 256 + tid];
    rsl[tid ^ 128] = s;
    __syncthreads();
    const int i0 = blockIdx.x * 256;
    const int i = i0 + tid;
    float dv = 0.f;
    if (i < Np) {
        const unsigned short* row = U + ((size_t)b * Np + i) * 256;
        float acc = 0.f;
        for (int q0 = 0; q0 < 256; q0 += 8) {
            u16x8 v = *(const u16x8*)(row + q0);
#pragma unroll
            for (int j = 0; j < 8; ++j) acc = fmaf(bf2f(v[j]), rsl[q0 + j], acc);
        }
        float d = 0.5f * acc;
        dv = d > 0.f ? rsqrtf(d) : 0.f;
        dinv[(size_t)b * Np + i] = dv;
    }
    dl[tid] = 0.5f * dv;
    __syncthreads();
    // coalesced Ud pass: 32 passes x 8 rows, threads cover 256 cols per row
    for (int pass = 0; pass < 32; ++pass) {
        int row = pass * 8 + (tid >> 5);
        int gi = i0 + row;
        if (gi < Np) {
            size_t off = ((size_t)b * Np + gi) * 256 + (tid & 31) * 8;
            u16x8 v = *(const u16x8*)(U + off);
            float sc = dl[row];
            u16x8 o;
#pragma unroll
            for (int j = 0; j < 8; ++j) o[j] = f2bf(bf2f(v[j]) * sc);
            *(u16x8*)(Ud + off) = o;
        }
    }
}

// d_out[b][c][n] = transpose(out_sm + BN(o_sm)); BN finalize fused in-block
__global__ __launch_bounds__(256) void xpoutbn_k(
    const float* __restrict__ out_sm, const unsigned short* __restrict__ oin,
    const float* __restrict__ ps, const float* __restrict__ ps2,
    const float* __restrict__ gamma, const float* __restrict__ beta,
    float* __restrict__ outp)
{
    __shared__ float tb[64][65];
    __shared__ float lsc[64], lsh[64];
    __shared__ float r1[256], r2[256];
    int b = blockIdx.z, c0 = blockIdx.y * 64, n0 = blockIdx.x * 64;
    int t = threadIdx.x;
    {
        int c = c0 + (t & 63), q4 = t >> 6;
        float a = 0.f, a2 = 0.f;
        for (int g = q4; g < 100; g += 4) {
            a += ps[(size_t)g * 256 + c];
            a2 += ps2[(size_t)g * 256 + c];
        }
        r1[t] = a; r2[t] = a2;
    }
    __syncthreads();
    if (t < 64) {
        float a = r1[t] + r1[64 + t] + r1[128 + t] + r1[192 + t];
        float a2 = r2[t] + r2[64 + t] + r2[128 + t] + r2[192 + t];
        const float inv = 1.f / (float)(Bc * NcT);
        float mean = a * inv;
        float var = a2 * inv - mean * mean;
        float sc = gamma[c0 + t] * rsqrtf(var + EPSc);
        lsc[t] = sc;
        lsh[t] = beta[c0 + t] - mean * sc;
    }
    __syncthreads();
    {
        int r = t >> 2, cb = (t & 3) * 16;
        size_t off = ((size_t)b * Np + n0 + r) * 256 + c0 + cb;
#pragma unroll
        for (int k = 0; k < 2; ++k) {
            float4 a0 = *(const float4*)(out_sm + off + 8 * k);
            float4 a1 = *(const float4*)(out_sm + off + 8 * k + 4);
            u16x8 ov = *(const u16x8*)(oin + off + 8 * k);
            tb[r][cb + 8*k + 0] = a0.x + fmaf(bf2f(ov[0]), lsc[cb + 8*k + 0], lsh[cb + 8*k + 0]);
            tb[r][cb + 8*k + 1] = a0.y + fmaf(bf2f(ov[1]), lsc[cb + 8*k + 1], lsh[cb + 8*k + 1]);
            tb[r][cb + 8*k + 2] = a0.z + fmaf(bf2f(ov[2]), lsc[cb + 8*k + 2], lsh[cb + 8*k + 2]);
            tb[r][cb + 8*k + 3] = a0.w + fmaf(bf2f(ov[3]), lsc[cb + 8*k + 3], lsh[cb + 8*k + 3]);
            tb[r][cb + 8*k + 4] = a1.x + fmaf(bf2f(ov[4]), lsc[cb + 8*k + 4], lsh[cb + 8*k + 4]);
            tb[r][cb + 8*k + 5] = a1.y + fmaf(bf2f(ov[5]), lsc[cb + 8*k + 5], lsh[cb + 8*k + 5]);
            tb[r][cb + 8*k + 6] = a1.z + fmaf(bf2f(ov[6]), lsc[cb + 8*k + 6], lsh[cb + 8*k + 6]);
            tb[r][cb + 8*k + 7] = a1.w + fmaf(bf2f(ov[7]), lsc[cb + 8*k + 7], lsh[cb + 8*k + 7]);
        }
    }
    __syncthreads();
    {
        int c = t >> 2, rb = (t & 3) * 16;
        float vv[16];
#pragma unroll
        for (int j = 0; j < 16; ++j) vv[j] = tb[rb + j][c];
        float* dst = outp + ((size_t)b * Cc + c0 + c) * NcT + n0 + rb;
#pragma unroll
        for (int k = 0; k < 4; ++k) {
            float4 v; v.x = vv[4*k]; v.y = vv[4*k+1]; v.z = vv[4*k+2]; v.w = vv[4*k+3];
            *(float4*)(dst + 4 * k) = v;
        }
    }
}

}  // namespace

extern "C" void kernel_launch(void* const* d_in, const int* in_sizes, int n_in,
                              void* d_out, int out_size, void* d_ws, size_t ws_size,
                              hipStream_t stream) {
    const float* x     = (const float*)d_in[0];
    const float* Wt    = (const float*)d_in[1];
    const float* Wp    = (const float*)d_in[2];
    const float* Wg    = (const float*)d_in[3];
    const float* W1    = (const float*)d_in[4];
    const float* W2    = (const float*)d_in[5];
    const float* gamma = (const float*)d_in[6];
    const float* beta  = (const float*)d_in[7];

    char* p = (char*)d_ws;
    auto alloc = [&](size_t bytes) { char* r = p; p += (bytes + 255) & ~(size_t)255; return r; };
    float*          out_sm = (float*)         alloc((size_t)Bc * Np * 256 * 4);
    unsigned short* outh   = (unsigned short*)alloc((size_t)Bc * Np * 256 * 2);
    unsigned short* U_sm   = (unsigned short*)alloc((size_t)Bc * Np * 256 * 2);
    unsigned short* U_cm   = (unsigned short*)alloc((size_t)Bc * 256 * Np * 2);
    unsigned short* Ud     = (unsigned short*)alloc((size_t)Bc * Np * 256 * 2);
    unsigned short* g_sm   = (unsigned short*)alloc((size_t)Bc * Np * Pc * 2);
    unsigned short* g_cmd  = (unsigned short*)alloc((size_t)Bc * Pc * Np * 2);
    unsigned short* o_sm   = (unsigned short*)alloc((size_t)Bc * Np * 256 * 2);
    unsigned short* Cpart  = (unsigned short*)alloc((size_t)KSn * Bc * 256 * Pc * 2);
    unsigned short* WMb    = (unsigned short*)alloc((size_t)Bc * Cc * 256 * 2);
    unsigned short* Wcomb  = (unsigned short*)alloc((size_t)Cc * Cc * 2);
    unsigned short* Wgh    = (unsigned short*)alloc((size_t)Sc * Pc * Cc * 2);
    unsigned short* W1h    = (unsigned short*)alloc((size_t)Sc * Cc * Pc * 2);
    unsigned short* W2h    = (unsigned short*)alloc((size_t)Sc * Cc * Pc * 2);
    float*          rp     = (float*)         alloc((size_t)100 * 256 * 4);
    float*          dinv   = (float*)         alloc((size_t)Bc * Np * 4);
    float*          ps     = (float*)         alloc((size_t)100 * 256 * 4);
    float*          ps2    = (float*)         alloc((size_t)100 * 256 * 4);

    const long NpC = (long)Np * 256;
    dim3 blk(256);

    prep_k<<<1344, blk, 0, stream>>>(x, Wt, Wp, Wg, W1, W2,
                                     Wcomb, Wgh, W1h, W2h, out_sm, outh);

    // U = relu([Wt;Wp] @ x): spatial-major + col-major + col sums
    {
        GP g{};
        g.A = outh; g.lda = 256; g.aB = NpC; g.aSl = 0;
        g.Bw = Wcomb; g.ldb = 256; g.bB = 0; g.bSl = 0;
        g.K = 256; g.nsl = 1;
        g.outSM = U_sm; g.ldsm = 256; g.smB = NpC; g.smSlice = 0;
        g.outCM = U_cm; g.cmB = (long)256 * Np;
        g.ps = rp;
        mgemm<128, 1, 1, false, 1, false, false, false>
            <<<dim3(2, 25, Bc), blk, 0, stream>>>(g);
    }

    dinvud_k<<<dim3(13, Bc), blk, 0, stream>>>(U_sm, rp, dinv, Ud);

    for (int s = 0; s < Sc; ++s) {
        // g = Wg[s] @ out  (FUSEBN applies previous stage's BN to residual,
        // with scale/shift reduced in-block from ps/ps2)
        {
            GP g{};
            g.A = outh; g.lda = 256; g.aB = NpC; g.aSl = 0;
            g.Bw = Wgh + (size_t)s * Pc * Cc; g.ldb = 256; g.bB = 0; g.bSl = 0;
            g.K = 256; g.nsl = 1;
            g.outSM = g_sm; g.ldsm = 128; g.smB = (long)Np * 128; g.smSlice = 0;
            g.outCM = g_cmd; g.cmB = (long)Pc * Np;
            g.dinv = dinv;
            g.oin = o_sm; g.resid = out_sm;
            g.ps = ps; g.ps2 = ps2;
            g.gammap = gamma + (size_t)(s - 1) * Cc;   // only used when s>0
            g.betap = beta + (size_t)(s - 1) * Cc;
            if (s == 0)
                mgemm<64, 0, 2, false, 0, false, false, false>
                    <<<dim3(1, 50, Bc), blk, 0, stream>>>(g);
            else
                mgemm<64, 0, 2, false, 0, true, false, false>
                    <<<dim3(1, 50, Bc), blk, 0, stream>>>(g);
        }
        // Cpart[ks][b][q^128][p] = partial_i U_cm[q][i] * g_cmd[p][i]
        {
            GP g{};
            g.A = U_cm; g.lda = Np; g.aB = (long)256 * Np; g.aSl = 0;
            g.Bw = g_cmd; g.ldb = Np; g.bB = (long)Pc * Np; g.bSl = 0;
            g.K = Np; g.kchunk = KCH; g.nsl = 1;
            g.outSM = Cpart; g.ldsm = 128; g.smB = (long)256 * Pc;
            g.smSlice = (long)Bc * 256 * Pc;
            mgemm<64, 0, 0, true, 0, false, true, false>
                <<<dim3(1, 4, KSn * Bc), blk, 0, stream>>>(g);
        }
        // WM[b][c][q] = sum_ks sum_p W1[c][p] * Cpart[ks][b][q][p]
        {
            GP g{};
            g.A = W1h + (size_t)s * Cc * Pc; g.lda = 128; g.aB = 0; g.aSl = 0;
            g.Bw = Cpart; g.ldb = 128; g.bB = (long)256 * Pc;
            g.bSl = (long)Bc * 256 * Pc;
            g.K = 128; g.nsl = KSn;
            g.outSM = WMb; g.ldsm = 256; g.smB = (long)Cc * 256; g.smSlice = 0;
            mgemm<64, 0, 0, false, 0, false, false, false>
                <<<dim3(2, 4, Bc), blk, 0, stream>>>(g);
        }
        // o = Ud @ WM^T + g @ W2^T  + BN partial stats
        {
            GP g{};
            g.A = Ud; g.lda = 256; g.aB = NpC; g.aSl = 0;
            g.Bw = WMb; g.ldb = 256; g.bB = (long)Cc * 256; g.bSl = 0;
            g.K = 256; g.nsl = 1;
            g.A2 = g_sm; g.lda2 = 128; g.aB2 = (long)Np * 128;
            g.B2 = W2h + (size_t)s * Cc * Pc; g.ldb2 = 128; g.bB2 = 0;
            g.K2 = 128;
            g.outSM = o_sm; g.ldsm = 256; g.smB = NpC; g.smSlice = 0;
            g.ps = ps; g.ps2 = ps2;
            mgemm<128, 0, 0, false, 2, false, false, true>
                <<<dim3(2, 25, Bc), blk, 0, stream>>>(g);
        }
    }

    // final: d_out = transpose(out_sm + BN(o_sm)), BN finalize fused
    xpoutbn_k<<<dim3(49, 4, Bc), blk, 0, stream>>>(
        out_sm, o_sm, ps, ps2, gamma + (size_t)(Sc - 1) * Cc,
        beta + (size_t)(Sc - 1) * Cc, (float*)d_out);
}

// Round 11
// 256.898 us; speedup vs baseline: 1.0939x; 1.0939x over previous
//
#include <hip/hip_runtime.h>

#define VMC(n) asm volatile("s_waitcnt vmcnt(" #n ")" ::: "memory")

namespace {

constexpr int Bc = 4;
constexpr int Cc = 256;
constexpr int Pc = 128;
constexpr int NcT = 3136;  // true spatial size 56*56
constexpr int Np = 3200;   // padded to 25*128
constexpr int Sc = 5;
constexpr int KSn = 5;     // split-K chunks for abt (3200 = 5*640)
constexpr int KCH = 640;
constexpr float EPSc = 1e-5f;

typedef __attribute__((ext_vector_type(8))) short bf16x8;
typedef __attribute__((ext_vector_type(4))) float f32x4;
typedef __attribute__((ext_vector_type(8))) unsigned short u16x8;
typedef __attribute__((ext_vector_type(4))) unsigned short u16x4;

__device__ inline float bf2f(unsigned short u) {
    return __uint_as_float(((unsigned)u) << 16);
}
__device__ inline unsigned short f2bf(float f) {
    unsigned u = __float_as_uint(f);
    return (unsigned short)((u + 0x7FFFu + ((u >> 16) & 1u)) >> 16);
}

struct GP {
    const unsigned short* A; int lda; long aB; long aSl;
    const unsigned short* Bw; int ldb; long bB; long bSl;
    const unsigned short* A2; int lda2; long aB2;
    const unsigned short* B2; int ldb2; long bB2;
    int K; int K2; int nsl; int kchunk;
    unsigned short* outSM; int ldsm; long smB; long smSlice;
    unsigned short* outCM; long cmB;
    float* ps; float* ps2;
    const float* bnsc; const float* bnsh;   // FUSEBN precomputed scale/shift
    const float* dinv;
    const unsigned short* oin;
    float* resid;
};

// ---------------------------------------------------------------------------
// MFMA GEMM: D[m][n] = sum over slices/loops of A[m][k]*B[n][k] (K-contig).
// Tile MT(m) x 128(n), 4 waves, K-step 64. Non-FUSEBN path: 4-buffer depth-3
// pipeline with counted vmcnt + raw s_barrier (one barrier per K-step, loads
// stay in flight across barriers). FUSEBN path: 2-buffer __syncthreads loop.
// Staging via global_load_lds(16B), granule swizzle phys = g ^ (row&7).
// EPI: 0 none, 1 relu.  CMOUT: 0 none, 1 plain col-major, 2 col-major*dinv[m]
// SPLITK: z=ks*4+b, K range [ks*kchunk,+kchunk), out += ks*smSlice
// BNSTAT: 1 col sums->ps, 2 +sumsq->ps2.  FUSEBN: A = resid + BN(oin), resid
// updated.  XORM: row-major store to row (m0^128)+r.  DUALK: 2nd loop (A2,B2).
// ---------------------------------------------------------------------------
template <int MT, int EPI, int CMOUT, bool SPLITK, int BNSTAT, bool FUSEBN,
          bool XORM, bool DUALK>
__global__ __launch_bounds__(256) void mgemm(GP p)
{
    constexpr int TBA = MT * 64 * 2;
    constexpr int TBB = 128 * 64 * 2;
    constexpr int BUF = TBA + TBB;
    constexpr int OTB = MT * 132 * 4;
    constexpr int LDSZ = (4 * BUF > OTB + 2048) ? 4 * BUF : (OTB + 2048);
    __shared__ __align__(16) char lds[LDSZ];

    int b, kstart;
    long smOff;
    if (SPLITK) {
        b = blockIdx.z & 3;
        int ks = blockIdx.z >> 2;
        kstart = ks * p.kchunk;
        smOff = (long)ks * p.smSlice;
    } else {
        b = blockIdx.z; kstart = 0; smOff = 0;
    }
    const int n0 = blockIdx.x * 128;
    const int m0 = blockIdx.y * MT;
    const int tid = threadIdx.x;
    const int w = tid >> 6, l = tid & 63;

    const unsigned short* Ab = p.A + (size_t)b * p.aB + (size_t)m0 * p.lda;
    const unsigned short* Bb = p.Bw + (size_t)b * p.bB + (size_t)n0 * p.ldb;

    const int srow8 = tid >> 3;                  // 0..31
    const int sgran = tid & 7;
    const int sswz = (sgran ^ (srow8 & 7)) * 8;  // swizzled source granule
    constexpr int AR = MT / 32;                  // A staging rounds

    constexpr int WC = (MT == 128) ? 2 : 4;      // waves along n
    constexpr int NB = 128 / WC / 16;            // B frags per wave
    const int wr = w / WC, wc = w % WC;

    f32x4 acc[4][NB] = {};
    float fup[AR][8];

    auto stage1 = [&](int buf, int sl, int k0) {
        char* base = lds + buf * BUF;
        const unsigned short* As = Ab + (size_t)sl * p.aSl + k0 + sswz;
#pragma unroll
        for (int j = 0; j < AR; ++j)
            __builtin_amdgcn_global_load_lds(
                (const __attribute__((address_space(1))) void*)
                    (As + (size_t)(j * 32 + srow8) * p.lda),
                (__attribute__((address_space(3))) void*)(base + j * 4096 + tid * 16),
                16, 0, 0);
        const unsigned short* Bs = Bb + (size_t)sl * p.bSl + k0 + sswz;
#pragma unroll
        for (int j = 0; j < 4; ++j)
            __builtin_amdgcn_global_load_lds(
                (const __attribute__((address_space(1))) void*)
                    (Bs + (size_t)(j * 32 + srow8) * p.ldb),
                (__attribute__((address_space(3))) void*)(base + TBA + j * 4096 + tid * 16),
                16, 0, 0);
    };

    auto stageB1 = [&](int buf, int k0) {
        char* base = lds + buf * BUF + TBA;
        const unsigned short* Bs = Bb + k0 + sswz;
#pragma unroll
        for (int j = 0; j < 4; ++j)
            __builtin_amdgcn_global_load_lds(
                (const __attribute__((address_space(1))) void*)
                    (Bs + (size_t)(j * 32 + srow8) * p.ldb),
                (__attribute__((address_space(3))) void*)(base + j * 4096 + tid * 16),
                16, 0, 0);
    };

    auto fbLoad = [&](int k0) {
        const float* scp = p.bnsc + k0 + sgran * 8;
        const float* shp = p.bnsh + k0 + sgran * 8;
        float4 s0 = *(const float4*)scp, s1 = *(const float4*)(scp + 4);
        float4 h0 = *(const float4*)shp, h1 = *(const float4*)(shp + 4);
#pragma unroll
        for (int j = 0; j < AR; ++j) {
            int row = j * 32 + srow8;
            int n = m0 + row;
            size_t off = ((size_t)b * Np + n) * 256 + k0 + sgran * 8;
            if (n < NcT) {
                u16x8 ov = *(const u16x8*)(p.oin + off);
                float4 r0 = *(const float4*)(p.resid + off);
                float4 r1 = *(const float4*)(p.resid + off + 4);
                fup[j][0] = r0.x + fmaf(bf2f(ov[0]), s0.x, h0.x);
                fup[j][1] = r0.y + fmaf(bf2f(ov[1]), s0.y, h0.y);
                fup[j][2] = r0.z + fmaf(bf2f(ov[2]), s0.z, h0.z);
                fup[j][3] = r0.w + fmaf(bf2f(ov[3]), s0.w, h0.w);
                fup[j][4] = r1.x + fmaf(bf2f(ov[4]), s1.x, h1.x);
                fup[j][5] = r1.y + fmaf(bf2f(ov[5]), s1.y, h1.y);
                fup[j][6] = r1.z + fmaf(bf2f(ov[6]), s1.z, h1.z);
                fup[j][7] = r1.w + fmaf(bf2f(ov[7]), s1.w, h1.w);
                float4 w0, w1;
                w0.x = fup[j][0]; w0.y = fup[j][1]; w0.z = fup[j][2]; w0.w = fup[j][3];
                w1.x = fup[j][4]; w1.y = fup[j][5]; w1.z = fup[j][6]; w1.w = fup[j][7];
                *(float4*)(p.resid + off) = w0;
                *(float4*)(p.resid + off + 4) = w1;
            } else {
#pragma unroll
                for (int i = 0; i < 8; ++i) fup[j][i] = 0.f;
            }
        }
    };
    auto fbWrite = [&](int buf) {
        char* base = lds + buf * BUF;
#pragma unroll
        for (int j = 0; j < AR; ++j) {
            int row = j * 32 + srow8;
            u16x8 hv;
#pragma unroll
            for (int i = 0; i < 8; ++i) hv[i] = f2bf(fup[j][i]);
            *(u16x8*)(base + row * 128 + ((sgran ^ (row & 7)) << 4)) = hv;
        }
    };

    auto compute = [&](int buf) {
        const char* base = lds + buf * BUF;
        const int lo = l & 15, gq = l >> 4;
#pragma unroll
        for (int kh = 0; kh < 2; ++kh) {
            const int lg = kh * 4 + gq;
            bf16x8 bf[NB];
#pragma unroll
            for (int c = 0; c < NB; ++c) {
                int brow = wc * (16 * NB) + c * 16 + lo;
                bf[c] = *(const bf16x8*)(base + TBA + brow * 128 +
                                         ((lg ^ (brow & 7)) << 4));
            }
#pragma unroll
            for (int r = 0; r < 4; ++r) {
                int arow = wr * 64 + r * 16 + lo;
                bf16x8 af = *(const bf16x8*)(base + arow * 128 +
                                             ((lg ^ (arow & 7)) << 4));
#pragma unroll
                for (int c = 0; c < NB; ++c)
                    acc[r][c] = __builtin_amdgcn_mfma_f32_16x16x32_bf16(
                        af, bf[c], acc[r][c], 0, 0, 0);
            }
        }
    };

    if constexpr (FUSEBN) {
        const int nst = p.K >> 6;    // nsl==1, no DUALK in this mode
        fbLoad(kstart);
        fbWrite(0);
        stageB1(0, kstart);
        __syncthreads();
        for (int s = 0; s < nst; ++s) {
            if (s + 1 < nst) {
                fbLoad(kstart + ((s + 1) << 6));
                stageB1((s + 1) & 1, kstart + ((s + 1) << 6));
            }
            compute(s & 1);
            if (s + 1 < nst) fbWrite((s + 1) & 1);
            __syncthreads();
        }
    } else {
        const int nsteps1 = (SPLITK ? p.kchunk : p.K) >> 6;
        const int spl2 = DUALK ? (p.K2 >> 6) : 0;
        const int loop1 = p.nsl * nsteps1;
        const int tot = loop1 + spl2;

        // second-loop staging (only instantiated for DUALK)
        const unsigned short* Ab2 = DUALK ?
            (p.A2 + (size_t)b * p.aB2 + (size_t)m0 * p.lda2) : nullptr;
        const unsigned short* Bb2 = DUALK ?
            (p.B2 + (size_t)b * p.bB2 + (size_t)n0 * p.ldb2) : nullptr;
        auto stage2 = [&](int buf, int k0) {
            if constexpr (DUALK) {
                char* base = lds + buf * BUF;
                const unsigned short* As = Ab2 + k0 + sswz;
#pragma unroll
                for (int j = 0; j < AR; ++j)
                    __builtin_amdgcn_global_load_lds(
                        (const __attribute__((address_space(1))) void*)
                            (As + (size_t)(j * 32 + srow8) * p.lda2),
                        (__attribute__((address_space(3))) void*)(base + j * 4096 + tid * 16),
                        16, 0, 0);
                const unsigned short* Bs = Bb2 + k0 + sswz;
#pragma unroll
                for (int j = 0; j < 4; ++j)
                    __builtin_amdgcn_global_load_lds(
                        (const __attribute__((address_space(1))) void*)
                            (Bs + (size_t)(j * 32 + srow8) * p.ldb2),
                        (__attribute__((address_space(3))) void*)(base + TBA + j * 4096 + tid * 16),
                        16, 0, 0);
            }
        };

        auto stage_g = [&](int buf, int g) {
            if (g < loop1) {
                int sl = g / nsteps1;
                int st = g - sl * nsteps1;
                stage1(buf, sl, kstart + (st << 6));
            } else {
                stage2(buf, (g - loop1) << 6);
            }
        };

        // depth-3 prologue (4 rotating buffers)
        stage_g(0, 0);
        if (1 < tot) stage_g(1, 1);
        if (2 < tot) stage_g(2, 2);
        for (int gs = 0; gs < tot; ++gs) {
            // counted wait: stage(gs) complete; deeper prefetch stays in flight
            if constexpr (MT == 64) {
                if (gs + 2 < tot) VMC(12);
                else if (gs + 1 < tot) VMC(6);
                else VMC(0);
            } else {
                if (gs + 2 < tot) VMC(16);
                else if (gs + 1 < tot) VMC(8);
                else VMC(0);
            }
            __builtin_amdgcn_s_barrier();
            __builtin_amdgcn_sched_barrier(0);
            if (gs + 3 < tot) stage_g((gs + 3) & 3, gs + 3);
            compute(gs & 3);
        }
        __syncthreads();   // all waves done before LDS reuse below
    }

    // stage accumulators to LDS f32 [MT][132]
    float* ot = (float*)lds;
    {
        const int lo = l & 15, gq = l >> 4;
#pragma unroll
        for (int r = 0; r < 4; ++r)
#pragma unroll
            for (int c = 0; c < NB; ++c)
#pragma unroll
                for (int j = 0; j < 4; ++j) {
                    float v = acc[r][c][j];
                    if (EPI == 1) v = fmaxf(v, 0.f);
                    ot[(wr * 64 + r * 16 + gq * 4 + j) * 132 +
                       wc * (16 * NB) + c * 16 + lo] = v;
                }
    }
    __syncthreads();

    {   // row-major store
        constexpr int TPR = 256 / MT;
        const int r = tid / TPR;
        const int c0 = (tid % TPR) * (MT / 2);
        const int m0s = XORM ? (m0 ^ 128) : m0;
        unsigned short* dst = p.outSM + (size_t)b * p.smB + smOff +
                              (size_t)(m0s + r) * p.ldsm + n0 + c0;
#pragma unroll
        for (int k = 0; k < MT / 16; ++k) {
            u16x8 o;
#pragma unroll
            for (int j = 0; j < 8; ++j) o[j] = f2bf(ot[r * 132 + c0 + 8 * k + j]);
            *(u16x8*)(dst + 8 * k) = o;
        }
    }

    if (CMOUT) {   // column-major store
        const int c = tid >> 1, r0 = (tid & 1) * (MT / 2);
        const float* dv = p.dinv + (size_t)b * Np + m0 + r0;
        unsigned short* dst = p.outCM + (size_t)b * p.cmB +
                              (size_t)(n0 + c) * Np + m0 + r0;
#pragma unroll
        for (int k = 0; k < MT / 16; ++k) {
            u16x8 o;
#pragma unroll
            for (int j = 0; j < 8; ++j) {
                float v = ot[(r0 + 8 * k + j) * 132 + c];
                if (CMOUT == 2) v *= dv[8 * k + j];
                o[j] = f2bf(v);
            }
            *(u16x8*)(dst + 8 * k) = o;
        }
    }

    if (BNSTAT) {
        float* p1 = (float*)(lds + OTB);
        float* p2 = p1 + 256;
        const int col = tid & 127, half = tid >> 7;
        float s = 0.f, s2 = 0.f;
#pragma unroll
        for (int i = 0; i < MT / 2; ++i) {
            float v = ot[(half * (MT / 2) + i) * 132 + col];
            s += v;
            if (BNSTAT == 2) s2 = fmaf(v, v, s2);
        }
        p1[half * 128 + col] = s;
        if (BNSTAT == 2) p2[half * 128 + col] = s2;
        __syncthreads();
        if (tid < 128) {
            float aa = p1[tid] + p1[128 + tid];
            size_t slot = ((size_t)b * gridDim.y + blockIdx.y) * 256 + n0 + tid;
            p.ps[slot] = aa;
            if (BNSTAT == 2) p.ps2[slot] = p2[tid] + p2[128 + tid];
        }
    }
}

// ---------------------------------------------------------------------------
// prep: weight f32->bf16 (544 items) + input transpose (800 items)
// ---------------------------------------------------------------------------
__global__ __launch_bounds__(256) void prep_k(
    const float* __restrict__ x, const float* __restrict__ Wt,
    const float* __restrict__ Wp, const float* __restrict__ Wg,
    const float* __restrict__ W1, const float* __restrict__ W2,
    unsigned short* __restrict__ Wcomb, unsigned short* __restrict__ Wgh,
    unsigned short* __restrict__ W1h, unsigned short* __restrict__ W2h,
    float* __restrict__ out_sm, unsigned short* __restrict__ outh)
{
    __shared__ float tb[64][65];
    int item = blockIdx.x;
    int t = threadIdx.x;
    if (item < 544) {
        size_t e = ((size_t)item * 256 + t) * 4;
        const float* src; unsigned short* dst;
        if (e < 32768)       { src = Wt + e;           dst = Wcomb + e; }
        else if (e < 65536)  { src = Wp + (e - 32768); dst = Wcomb + e; }
        else if (e < 229376) { size_t o = e - 65536;  src = Wg + o; dst = Wgh + o; }
        else if (e < 393216) { size_t o = e - 229376; src = W1 + o; dst = W1h + o; }
        else                 { size_t o = e - 393216; src = W2 + o; dst = W2h + o; }
        float4 v = *(const float4*)src;
        u16x4 t4;
        t4[0] = f2bf(v.x); t4[1] = f2bf(v.y); t4[2] = f2bf(v.z); t4[3] = f2bf(v.w);
        *(u16x4*)dst = t4;
        return;
    }
    int it = item - 544;
    int nx = it % 50, cy = (it / 50) % 4, b = it / 200;
    int c0 = cy * 64, n0 = nx * 64;
    const bool pad = (n0 >= NcT);
    if (!pad) {
        int ci = t >> 2, nb = (t & 3) * 16;
        const float* src = x + ((size_t)b * Cc + c0 + ci) * NcT + n0 + nb;
#pragma unroll
        for (int k = 0; k < 4; ++k) {
            float4 v = *(const float4*)(src + 4 * k);
            tb[ci][nb + 4 * k + 0] = v.x; tb[ci][nb + 4 * k + 1] = v.y;
            tb[ci][nb + 4 * k + 2] = v.z; tb[ci][nb + 4 * k + 3] = v.w;
        }
    }
    __syncthreads();
    int r = t >> 2, cb = (t & 3) * 16;
    size_t off = ((size_t)b * Np + n0 + r) * 256 + c0 + cb;
    float vv[16];
#pragma unroll
    for (int j = 0; j < 16; ++j) vv[j] = pad ? 0.f : tb[cb + j][r];
    float* dst = out_sm + off;
#pragma unroll
    for (int k = 0; k < 4; ++k) {
        float4 v; v.x = vv[4*k]; v.y = vv[4*k+1]; v.z = vv[4*k+2]; v.w = vv[4*k+3];
        *(float4*)(dst + 4 * k) = v;
    }
    u16x8 h1, h2;
#pragma unroll
    for (int j = 0; j < 8; ++j) { h1[j] = f2bf(vv[j]); h2[j] = f2bf(vv[8 + j]); }
    unsigned short* dh = outh + off;
    *(u16x8*)dh = h1;
    *(u16x8*)(dh + 8) = h2;
}

// dinv + Ud fused: dinv[b][i] = d>0 ? rsqrt(d) : 0; Ud[b][i][q] = 0.5*dinv*U
__global__ __launch_bounds__(256) void dinvud_k(
    const unsigned short* __restrict__ U, const float* __restrict__ rp,
    float* __restrict__ dinv, unsigned short* __restrict__ Ud)
{
    __shared__ float rsl[256];
    __shared__ float dl[256];
    int b = blockIdx.y, tid = threadIdx.x;
    float s = 0.f;
    for (int j = 0; j < 25; ++j) s += rp[((size_t)b * 25 + j) * 256 + tid];
    rsl[tid ^ 128] = s;
    __syncthreads();
    const int i0 = blockIdx.x * 256;
    const int i = i0 + tid;
    float dv = 0.f;
    if (i < Np) {
        const unsigned short* row = U + ((size_t)b * Np + i) * 256;
        float acc = 0.f;
        for (int q0 = 0; q0 < 256; q0 += 8) {
            u16x8 v = *(const u16x8*)(row + q0);
#pragma unroll
            for (int j = 0; j < 8; ++j) acc = fmaf(bf2f(v[j]), rsl[q0 + j], acc);
        }
        float d = 0.5f * acc;
        dv = d > 0.f ? rsqrtf(d) : 0.f;
        dinv[(size_t)b * Np + i] = dv;
    }
    dl[tid] = 0.5f * dv;
    __syncthreads();
    for (int pass = 0; pass < 32; ++pass) {
        int row = pass * 8 + (tid >> 5);
        int gi = i0 + row;
        if (gi < Np) {
            size_t off = ((size_t)b * Np + gi) * 256 + (tid & 31) * 8;
            u16x8 v = *(const u16x8*)(U + off);
            float sc = dl[row];
            u16x8 o;
#pragma unroll
            for (int j = 0; j < 8; ++j) o[j] = f2bf(bf2f(v[j]) * sc);
            *(u16x8*)(Ud + off) = o;
        }
    }
}

// BN finalize: 16 blocks x 16 channels; 100 partial groups
__global__ __launch_bounds__(256) void bnfin_k(
    const float* __restrict__ ps, const float* __restrict__ ps2,
    const float* __restrict__ gamma, const float* __restrict__ beta,
    float* __restrict__ scale, float* __restrict__ shift)
{
    __shared__ float l1[256], l2[256];
    int t = threadIdx.x;
    int c = blockIdx.x * 16 + (t & 15);
    int gl = t >> 4;
    float a = 0.f, a2 = 0.f;
    for (int g = gl; g < 100; g += 16) {
        a += ps[(size_t)g * 256 + c];
        a2 += ps2[(size_t)g * 256 + c];
    }
    l1[t] = a; l2[t] = a2;
    __syncthreads();
    if (gl == 0) {
#pragma unroll
        for (int j = 1; j < 16; ++j) {
            a += l1[j * 16 + (t & 15)];
            a2 += l2[j * 16 + (t & 15)];
        }
        const float inv = 1.f / (float)(Bc * NcT);
        float mean = a * inv;
        float var = a2 * inv - mean * mean;
        float sc = gamma[c] * rsqrtf(var + EPSc);
        scale[c] = sc;
        shift[c] = beta[c] - mean * sc;
    }
}

// d_out[b][c][n] = transpose(out_sm + BN(o_sm))   (final stage fused)
__global__ __launch_bounds__(256) void xpoutbn_k(
    const float* __restrict__ out_sm, const unsigned short* __restrict__ oin,
    const float* __restrict__ scale, const float* __restrict__ shift,
    float* __restrict__ outp)
{
    __shared__ float tb[64][65];
    __shared__ float lsc[64], lsh[64];
    int b = blockIdx.z, c0 = blockIdx.y * 64, n0 = blockIdx.x * 64;
    int t = threadIdx.x;
    if (t < 64) { lsc[t] = scale[c0 + t]; lsh[t] = shift[c0 + t]; }
    __syncthreads();
    {
        int r = t >> 2, cb = (t & 3) * 16;
        size_t off = ((size_t)b * Np + n0 + r) * 256 + c0 + cb;
#pragma unroll
        for (int k = 0; k < 2; ++k) {
            float4 a0 = *(const float4*)(out_sm + off + 8 * k);
            float4 a1 = *(const float4*)(out_sm + off + 8 * k + 4);
            u16x8 ov = *(const u16x8*)(oin + off + 8 * k);
            tb[r][cb + 8*k + 0] = a0.x + fmaf(bf2f(ov[0]), lsc[cb + 8*k + 0], lsh[cb + 8*k + 0]);
            tb[r][cb + 8*k + 1] = a0.y + fmaf(bf2f(ov[1]), lsc[cb + 8*k + 1], lsh[cb + 8*k + 1]);
            tb[r][cb + 8*k + 2] = a0.z + fmaf(bf2f(ov[2]), lsc[cb + 8*k + 2], lsh[cb + 8*k + 2]);
            tb[r][cb + 8*k + 3] = a0.w + fmaf(bf2f(ov[3]), lsc[cb + 8*k + 3], lsh[cb + 8*k + 3]);
            tb[r][cb + 8*k + 4] = a1.x + fmaf(bf2f(ov[4]), lsc[cb + 8*k + 4], lsh[cb + 8*k + 4]);
            tb[r][cb + 8*k + 5] = a1.y + fmaf(bf2f(ov[5]), lsc[cb + 8*k + 5], lsh[cb + 8*k + 5]);
            tb[r][cb + 8*k + 6] = a1.z + fmaf(bf2f(ov[6]), lsc[cb + 8*k + 6], lsh[cb + 8*k + 6]);
            tb[r][cb + 8*k + 7] = a1.w + fmaf(bf2f(ov[7]), lsc[cb + 8*k + 7], lsh[cb + 8*k + 7]);
        }
    }
    __syncthreads();
    {
        int c = t >> 2, rb = (t & 3) * 16;
        float vv[16];
#pragma unroll
        for (int j = 0; j < 16; ++j) vv[j] = tb[rb + j][c];
        float* dst = outp + ((size_t)b * Cc + c0 + c) * NcT + n0 + rb;
#pragma unroll
        for (int k = 0; k < 4; ++k) {
            float4 v; v.x = vv[4*k]; v.y = vv[4*k+1]; v.z = vv[4*k+2]; v.w = vv[4*k+3];
            *(float4*)(dst + 4 * k) = v;
        }
    }
}

}  // namespace

extern "C" void kernel_launch(void* const* d_in, const int* in_sizes, int n_in,
                              void* d_out, int out_size, void* d_ws, size_t ws_size,
                              hipStream_t stream) {
    const float* x     = (const float*)d_in[0];
    const float* Wt    = (const float*)d_in[1];
    const float* Wp    = (const float*)d_in[2];
    const float* Wg    = (const float*)d_in[3];
    const float* W1    = (const float*)d_in[4];
    const float* W2    = (const float*)d_in[5];
    const float* gamma = (const float*)d_in[6];
    const float* beta  = (const float*)d_in[7];

    char* p = (char*)d_ws;
    auto alloc = [&](size_t bytes) { char* r = p; p += (bytes + 255) & ~(size_t)255; return r; };
    float*          out_sm = (float*)         alloc((size_t)Bc * Np * 256 * 4);
    unsigned short* outh   = (unsigned short*)alloc((size_t)Bc * Np * 256 * 2);
    unsigned short* U_sm   = (unsigned short*)alloc((size_t)Bc * Np * 256 * 2);
    unsigned short* U_cm   = (unsigned short*)alloc((size_t)Bc * 256 * Np * 2);
    unsigned short* Ud     = (unsigned short*)alloc((size_t)Bc * Np * 256 * 2);
    unsigned short* g_sm   = (unsigned short*)alloc((size_t)Bc * Np * Pc * 2);
    unsigned short* g_cmd  = (unsigned short*)alloc((size_t)Bc * Pc * Np * 2);
    unsigned short* o_sm   = (unsigned short*)alloc((size_t)Bc * Np * 256 * 2);
    unsigned short* Cpart  = (unsigned short*)alloc((size_t)KSn * Bc * 256 * Pc * 2);
    unsigned short* WMb    = (unsigned short*)alloc((size_t)Bc * Cc * 256 * 2);
    unsigned short* Wcomb  = (unsigned short*)alloc((size_t)Cc * Cc * 2);
    unsigned short* Wgh    = (unsigned short*)alloc((size_t)Sc * Pc * Cc * 2);
    unsigned short* W1h    = (unsigned short*)alloc((size_t)Sc * Cc * Pc * 2);
    unsigned short* W2h    = (unsigned short*)alloc((size_t)Sc * Cc * Pc * 2);
    float*          rp     = (float*)         alloc((size_t)100 * 256 * 4);
    float*          dinv   = (float*)         alloc((size_t)Bc * Np * 4);
    float*          ps     = (float*)         alloc((size_t)100 * 256 * 4);
    float*          ps2    = (float*)         alloc((size_t)100 * 256 * 4);
    float*          scale  = (float*)         alloc(256 * 4);
    float*          shiftb = (float*)         alloc(256 * 4);

    const long NpC = (long)Np * 256;
    dim3 blk(256);

    prep_k<<<1344, blk, 0, stream>>>(x, Wt, Wp, Wg, W1, W2,
                                     Wcomb, Wgh, W1h, W2h, out_sm, outh);

    // U = relu([Wt;Wp] @ x): spatial-major + col-major + col sums
    {
        GP g{};
        g.A = outh; g.lda = 256; g.aB = NpC; g.aSl = 0;
        g.Bw = Wcomb; g.ldb = 256; g.bB = 0; g.bSl = 0;
        g.K = 256; g.nsl = 1;
        g.outSM = U_sm; g.ldsm = 256; g.smB = NpC; g.smSlice = 0;
        g.outCM = U_cm; g.cmB = (long)256 * Np;
        g.ps = rp;
        mgemm<128, 1, 1, false, 1, false, false, false>
            <<<dim3(2, 25, Bc), blk, 0, stream>>>(g);
    }

    dinvud_k<<<dim3(13, Bc), blk, 0, stream>>>(U_sm, rp, dinv, Ud);

    for (int s = 0; s < Sc; ++s) {
        // g = Wg[s] @ out  (FUSEBN applies previous stage's BN to residual)
        {
            GP g{};
            g.A = outh; g.lda = 256; g.aB = NpC; g.aSl = 0;
            g.Bw = Wgh + (size_t)s * Pc * Cc; g.ldb = 256; g.bB = 0; g.bSl = 0;
            g.K = 256; g.nsl = 1;
            g.outSM = g_sm; g.ldsm = 128; g.smB = (long)Np * 128; g.smSlice = 0;
            g.outCM = g_cmd; g.cmB = (long)Pc * Np;
            g.dinv = dinv;
            g.oin = o_sm; g.bnsc = scale; g.bnsh = shiftb; g.resid = out_sm;
            if (s == 0)
                mgemm<64, 0, 2, false, 0, false, false, false>
                    <<<dim3(1, 50, Bc), blk, 0, stream>>>(g);
            else
                mgemm<64, 0, 2, false, 0, true, false, false>
                    <<<dim3(1, 50, Bc), blk, 0, stream>>>(g);
        }
        // Cpart[ks][b][q^128][p] = partial_i U_cm[q][i] * g_cmd[p][i]
        {
            GP g{};
            g.A = U_cm; g.lda = Np; g.aB = (long)256 * Np; g.aSl = 0;
            g.Bw = g_cmd; g.ldb = Np; g.bB = (long)Pc * Np; g.bSl = 0;
            g.K = Np; g.kchunk = KCH; g.nsl = 1;
            g.outSM = Cpart; g.ldsm = 128; g.smB = (long)256 * Pc;
            g.smSlice = (long)Bc * 256 * Pc;
            mgemm<64, 0, 0, true, 0, false, true, false>
                <<<dim3(1, 4, KSn * Bc), blk, 0, stream>>>(g);
        }
        // WM[b][c][q] = sum_ks sum_p W1[c][p] * Cpart[ks][b][q][p]
        {
            GP g{};
            g.A = W1h + (size_t)s * Cc * Pc; g.lda = 128; g.aB = 0; g.aSl = 0;
            g.Bw = Cpart; g.ldb = 128; g.bB = (long)256 * Pc;
            g.bSl = (long)Bc * 256 * Pc;
            g.K = 128; g.nsl = KSn;
            g.outSM = WMb; g.ldsm = 256; g.smB = (long)Cc * 256; g.smSlice = 0;
            mgemm<64, 0, 0, false, 0, false, false, false>
                <<<dim3(2, 4, Bc), blk, 0, stream>>>(g);
        }
        // o = Ud @ WM^T + g @ W2^T  + BN partial stats
        {
            GP g{};
            g.A = Ud; g.lda = 256; g.aB = NpC; g.aSl = 0;
            g.Bw = WMb; g.ldb = 256; g.bB = (long)Cc * 256; g.bSl = 0;
            g.K = 256; g.nsl = 1;
            g.A2 = g_sm; g.lda2 = 128; g.aB2 = (long)Np * 128;
            g.B2 = W2h + (size_t)s * Cc * Pc; g.ldb2 = 128; g.bB2 = 0;
            g.K2 = 128;
            g.outSM = o_sm; g.ldsm = 256; g.smB = NpC; g.smSlice = 0;
            g.ps = ps; g.ps2 = ps2;
            mgemm<128, 0, 0, false, 2, false, false, true>
                <<<dim3(2, 25, Bc), blk, 0, stream>>>(g);
        }
        bnfin_k<<<16, blk, 0, stream>>>(ps, ps2, gamma + s * Cc, beta + s * Cc,
                                        scale, shiftb);
    }

    // final: d_out = transpose(out_sm + BN(o_sm))
    xpoutbn_k<<<dim3(49, 4, Bc), blk, 0, stream>>>(out_sm, o_sm, scale, shiftb,
                                                   (float*)d_out);
}

// Round 12
// 250.381 us; speedup vs baseline: 1.1223x; 1.0260x over previous
//
#include <hip/hip_runtime.h>

#define VMC(n) asm volatile("s_waitcnt vmcnt(" #n ")" ::: "memory")
#define LGKM0() asm volatile("s_waitcnt lgkmcnt(0)" ::: "memory")

namespace {

constexpr int Bc = 4;
constexpr int Cc = 256;
constexpr int Pc = 128;
constexpr int NcT = 3136;  // true spatial size 56*56
constexpr int Np = 3200;   // padded to 25*128
constexpr int Sc = 5;
constexpr int KSn = 5;     // split-K chunks for abt (3200 = 5*640)
constexpr int KCH = 640;
constexpr float EPSc = 1e-5f;

typedef __attribute__((ext_vector_type(8))) short bf16x8;
typedef __attribute__((ext_vector_type(4))) float f32x4;
typedef __attribute__((ext_vector_type(8))) unsigned short u16x8;
typedef __attribute__((ext_vector_type(4))) unsigned short u16x4;

__device__ inline float bf2f(unsigned short u) {
    return __uint_as_float(((unsigned)u) << 16);
}
__device__ inline unsigned short f2bf(float f) {
    unsigned u = __float_as_uint(f);
    return (unsigned short)((u + 0x7FFFu + ((u >> 16) & 1u)) >> 16);
}

struct GP {
    const unsigned short* A; int lda; long aB; long aSl;
    const unsigned short* Bw; int ldb; long bB; long bSl;
    const unsigned short* A2; int lda2; long aB2;
    const unsigned short* B2; int ldb2; long bB2;
    int K; int K2; int nsl; int kchunk;
    unsigned short* outSM; int ldsm; long smB; long smSlice;
    unsigned short* outCM; long cmB;
    float* ps; float* ps2;
    const float* bnsc; const float* bnsh;   // FUSEBN precomputed scale/shift
    const float* dinv;
    const unsigned short* oin;
    float* resid;
};

// ---------------------------------------------------------------------------
// MFMA GEMM: D[m][n] = sum over slices/loops of A[m][k]*B[n][k] (K-contig).
// Tile MT(m) x 128(n), 4 waves, K-step 64. Non-FUSEBN path: 4-buffer depth-3
// pipeline with counted vmcnt + raw s_barrier. FUSEBN path: explicit 4-step
// (K=256) depth-2 register-prefetch (fbIssue/fbFin split) pipeline.
// Staging via global_load_lds(16B), granule swizzle phys = g ^ (row&7).
// EPI: 0 none, 1 relu.  CMOUT: 0 none, 1 plain col-major, 2 col-major*dinv[m]
// SPLITK: z=ks*4+b, K range [ks*kchunk,+kchunk), out += ks*smSlice
// BNSTAT: 1 col sums->ps, 2 +sumsq->ps2.  FUSEBN: A = resid + BN(oin), resid
// updated.  XORM: row-major store to row (m0^128)+r.  DUALK: 2nd loop (A2,B2);
// accumulators scaled by 0.5*dinv[m] between loop1 and loop2.
// ---------------------------------------------------------------------------
template <int MT, int EPI, int CMOUT, bool SPLITK, int BNSTAT, bool FUSEBN,
          bool XORM, bool DUALK>
__global__ __launch_bounds__(256) void mgemm(GP p)
{
    constexpr int TBA = MT * 64 * 2;
    constexpr int TBB = 128 * 64 * 2;
    constexpr int BUF = TBA + TBB;
    constexpr int OTB = MT * 132 * 4;
    constexpr int LDSZ = (4 * BUF > OTB + 2048) ? 4 * BUF : (OTB + 2048);
    __shared__ __align__(16) char lds[LDSZ];

    int b, kstart;
    long smOff;
    if (SPLITK) {
        b = blockIdx.z & 3;
        int ks = blockIdx.z >> 2;
        kstart = ks * p.kchunk;
        smOff = (long)ks * p.smSlice;
    } else {
        b = blockIdx.z; kstart = 0; smOff = 0;
    }
    const int n0 = blockIdx.x * 128;
    const int m0 = blockIdx.y * MT;
    const int tid = threadIdx.x;
    const int w = tid >> 6, l = tid & 63;

    const unsigned short* Ab = p.A + (size_t)b * p.aB + (size_t)m0 * p.lda;
    const unsigned short* Bb = p.Bw + (size_t)b * p.bB + (size_t)n0 * p.ldb;

    const int srow8 = tid >> 3;                  // 0..31
    const int sgran = tid & 7;
    const int sswz = (sgran ^ (srow8 & 7)) * 8;  // swizzled source granule
    constexpr int AR = MT / 32;                  // A staging rounds

    constexpr int WC = (MT == 128) ? 2 : 4;      // waves along n
    constexpr int NB = 128 / WC / 16;            // B frags per wave
    const int wr = w / WC, wc = w % WC;

    f32x4 acc[4][NB] = {};

    // DUALK: preload 0.5*dinv for this lane's accumulator rows (issued first
    // so these loads are oldest and retire before any counted wait matters)
    float4 dvv[4];
    if constexpr (DUALK) {
#pragma unroll
        for (int r = 0; r < 4; ++r) {
            float4 v = *(const float4*)(p.dinv + (size_t)b * Np + m0 +
                                        wr * 64 + r * 16 + (l >> 4) * 4);
            v.x *= 0.5f; v.y *= 0.5f; v.z *= 0.5f; v.w *= 0.5f;
            dvv[r] = v;
        }
    }

    auto stage1 = [&](int buf, int sl, int k0) {
        char* base = lds + buf * BUF;
        const unsigned short* As = Ab + (size_t)sl * p.aSl + k0 + sswz;
#pragma unroll
        for (int j = 0; j < AR; ++j)
            __builtin_amdgcn_global_load_lds(
                (const __attribute__((address_space(1))) void*)
                    (As + (size_t)(j * 32 + srow8) * p.lda),
                (__attribute__((address_space(3))) void*)(base + j * 4096 + tid * 16),
                16, 0, 0);
        const unsigned short* Bs = Bb + (size_t)sl * p.bSl + k0 + sswz;
#pragma unroll
        for (int j = 0; j < 4; ++j)
            __builtin_amdgcn_global_load_lds(
                (const __attribute__((address_space(1))) void*)
                    (Bs + (size_t)(j * 32 + srow8) * p.ldb),
                (__attribute__((address_space(3))) void*)(base + TBA + j * 4096 + tid * 16),
                16, 0, 0);
    };

    auto stageB1 = [&](int buf, int k0) {
        char* base = lds + buf * BUF + TBA;
        const unsigned short* Bs = Bb + k0 + sswz;
#pragma unroll
        for (int j = 0; j < 4; ++j)
            __builtin_amdgcn_global_load_lds(
                (const __attribute__((address_space(1))) void*)
                    (Bs + (size_t)(j * 32 + srow8) * p.ldb),
                (__attribute__((address_space(3))) void*)(base + j * 4096 + tid * 16),
                16, 0, 0);
    };

    auto compute = [&](int buf) {
        const char* base = lds + buf * BUF;
        const int lo = l & 15, gq = l >> 4;
#pragma unroll
        for (int kh = 0; kh < 2; ++kh) {
            const int lg = kh * 4 + gq;
            bf16x8 bf[NB];
#pragma unroll
            for (int c = 0; c < NB; ++c) {
                int brow = wc * (16 * NB) + c * 16 + lo;
                bf[c] = *(const bf16x8*)(base + TBA + brow * 128 +
                                         ((lg ^ (brow & 7)) << 4));
            }
#pragma unroll
            for (int r = 0; r < 4; ++r) {
                int arow = wr * 64 + r * 16 + lo;
                bf16x8 af = *(const bf16x8*)(base + arow * 128 +
                                             ((lg ^ (arow & 7)) << 4));
#pragma unroll
                for (int c = 0; c < NB; ++c)
                    acc[r][c] = __builtin_amdgcn_mfma_f32_16x16x32_bf16(
                        af, bf[c], acc[r][c], 0, 0, 0);
            }
        }
    };

    if constexpr (FUSEBN) {
        // K == 256: explicit 4-step, depth-2 register prefetch, 4 buffers.
        struct FB {
            u16x8 ov[AR]; float4 r0[AR], r1[AR];
            float4 s0, s1, h0, h1; int k0;
        };
        FB fA, fB;
        auto fbIssue = [&](FB& f, int k0) {   // 10 vm loads
            f.k0 = k0;
            f.s0 = *(const float4*)(p.bnsc + k0 + sgran * 8);
            f.s1 = *(const float4*)(p.bnsc + k0 + sgran * 8 + 4);
            f.h0 = *(const float4*)(p.bnsh + k0 + sgran * 8);
            f.h1 = *(const float4*)(p.bnsh + k0 + sgran * 8 + 4);
#pragma unroll
            for (int j = 0; j < AR; ++j) {
                size_t off = ((size_t)b * Np + (m0 + j * 32 + srow8)) * 256 +
                             k0 + sgran * 8;
                f.ov[j] = *(const u16x8*)(p.oin + off);
                f.r0[j] = *(const float4*)(p.resid + off);
                f.r1[j] = *(const float4*)(p.resid + off + 4);
            }
        };
        auto fbFin = [&](FB& f, int buf) {    // 4 vm stores + AR ds_writes
            char* base = lds + buf * BUF;
#pragma unroll
            for (int j = 0; j < AR; ++j) {
                int row = j * 32 + srow8;
                int n = m0 + row;
                size_t off = ((size_t)b * Np + n) * 256 + f.k0 + sgran * 8;
                bool real = (n < NcT);
                float fu[8];
                fu[0] = real ? f.r0[j].x + fmaf(bf2f(f.ov[j][0]), f.s0.x, f.h0.x) : 0.f;
                fu[1] = real ? f.r0[j].y + fmaf(bf2f(f.ov[j][1]), f.s0.y, f.h0.y) : 0.f;
                fu[2] = real ? f.r0[j].z + fmaf(bf2f(f.ov[j][2]), f.s0.z, f.h0.z) : 0.f;
                fu[3] = real ? f.r0[j].w + fmaf(bf2f(f.ov[j][3]), f.s0.w, f.h0.w) : 0.f;
                fu[4] = real ? f.r1[j].x + fmaf(bf2f(f.ov[j][4]), f.s1.x, f.h1.x) : 0.f;
                fu[5] = real ? f.r1[j].y + fmaf(bf2f(f.ov[j][5]), f.s1.y, f.h1.y) : 0.f;
                fu[6] = real ? f.r1[j].z + fmaf(bf2f(f.ov[j][6]), f.s1.z, f.h1.z) : 0.f;
                fu[7] = real ? f.r1[j].w + fmaf(bf2f(f.ov[j][7]), f.s1.w, f.h1.w) : 0.f;
                float4 w0, w1;
                w0.x = fu[0]; w0.y = fu[1]; w0.z = fu[2]; w0.w = fu[3];
                w1.x = fu[4]; w1.y = fu[5]; w1.z = fu[6]; w1.w = fu[7];
                *(float4*)(p.resid + off) = w0;
                *(float4*)(p.resid + off + 4) = w1;
                u16x8 hv;
#pragma unroll
                for (int i = 0; i < 8; ++i) hv[i] = f2bf(fu[i]);
                *(u16x8*)(base + row * 128 + ((sgran ^ (row & 7)) << 4)) = hv;
            }
        };

        fbIssue(fA, kstart);        stageB1(0, kstart);
        fbIssue(fB, kstart + 64);   stageB1(1, kstart + 64);
        // it0: drain fbA(10)+sB0(4); keep fbB+sB1 in flight
        VMC(14);
        fbFin(fA, 0);
        fbIssue(fA, kstart + 128);  stageB1(2, kstart + 128);
        LGKM0();
        __builtin_amdgcn_s_barrier();
        __builtin_amdgcn_sched_barrier(0);
        compute(0);
        // it1: [fbB sB1][st0][fbA' sB2]=32 -> 18 keeps st0+fbA'+sB2
        VMC(18);
        fbFin(fB, 1);
        fbIssue(fB, kstart + 192);  stageB1(3, kstart + 192);
        LGKM0();
        __builtin_amdgcn_s_barrier();
        __builtin_amdgcn_sched_barrier(0);
        compute(1);
        // it2: [st0][fbA' sB2][st1][fbB' sB3]=36 -> 18 keeps st1+fbB'+sB3
        VMC(18);
        fbFin(fA, 2);
        LGKM0();
        __builtin_amdgcn_s_barrier();
        __builtin_amdgcn_sched_barrier(0);
        compute(2);
        // it3: [st1][fbB' sB3][st2]=22 -> 4 keeps st2
        VMC(4);
        fbFin(fB, 3);
        LGKM0();
        __builtin_amdgcn_s_barrier();
        __builtin_amdgcn_sched_barrier(0);
        compute(3);
        __syncthreads();
    } else {
        const int nsteps1 = (SPLITK ? p.kchunk : p.K) >> 6;
        const int spl2 = DUALK ? (p.K2 >> 6) : 0;
        const int loop1 = p.nsl * nsteps1;
        const int tot = loop1 + spl2;

        const unsigned short* Ab2 = DUALK ?
            (p.A2 + (size_t)b * p.aB2 + (size_t)m0 * p.lda2) : nullptr;
        const unsigned short* Bb2 = DUALK ?
            (p.B2 + (size_t)b * p.bB2 + (size_t)n0 * p.ldb2) : nullptr;
        auto stage2 = [&](int buf, int k0) {
            if constexpr (DUALK) {
                char* base = lds + buf * BUF;
                const unsigned short* As = Ab2 + k0 + sswz;
#pragma unroll
                for (int j = 0; j < AR; ++j)
                    __builtin_amdgcn_global_load_lds(
                        (const __attribute__((address_space(1))) void*)
                            (As + (size_t)(j * 32 + srow8) * p.lda2),
                        (__attribute__((address_space(3))) void*)(base + j * 4096 + tid * 16),
                        16, 0, 0);
                const unsigned short* Bs = Bb2 + k0 + sswz;
#pragma unroll
                for (int j = 0; j < 4; ++j)
                    __builtin_amdgcn_global_load_lds(
                        (const __attribute__((address_space(1))) void*)
                            (Bs + (size_t)(j * 32 + srow8) * p.ldb2),
                        (__attribute__((address_space(3))) void*)(base + TBA + j * 4096 + tid * 16),
                        16, 0, 0);
            }
        };

        auto stage_g = [&](int buf, int g) {
            if (g < loop1) {
                int sl = g / nsteps1;
                int st = g - sl * nsteps1;
                stage1(buf, sl, kstart + (st << 6));
            } else {
                stage2(buf, (g - loop1) << 6);
            }
        };

        stage_g(0, 0);
        if (1 < tot) stage_g(1, 1);
        if (2 < tot) stage_g(2, 2);
        for (int gs = 0; gs < tot; ++gs) {
            if constexpr (MT == 64) {
                if (gs + 2 < tot) VMC(12);
                else if (gs + 1 < tot) VMC(6);
                else VMC(0);
            } else {
                if (gs + 2 < tot) VMC(16);
                else if (gs + 1 < tot) VMC(8);
                else VMC(0);
            }
            __builtin_amdgcn_s_barrier();
            __builtin_amdgcn_sched_barrier(0);
            if (gs + 3 < tot) stage_g((gs + 3) & 3, gs + 3);
            compute(gs & 3);
            if constexpr (DUALK) {
                if (gs == loop1 - 1) {   // scale loop1 accumulation by 0.5*dinv[m]
#pragma unroll
                    for (int r = 0; r < 4; ++r) {
#pragma unroll
                        for (int c = 0; c < NB; ++c) {
                            acc[r][c][0] *= dvv[r].x;
                            acc[r][c][1] *= dvv[r].y;
                            acc[r][c][2] *= dvv[r].z;
                            acc[r][c][3] *= dvv[r].w;
                        }
                    }
                }
            }
        }
        __syncthreads();
    }

    // stage accumulators to LDS f32 [MT][132]
    float* ot = (float*)lds;
    {
        const int lo = l & 15, gq = l >> 4;
#pragma unroll
        for (int r = 0; r < 4; ++r)
#pragma unroll
            for (int c = 0; c < NB; ++c)
#pragma unroll
                for (int j = 0; j < 4; ++j) {
                    float v = acc[r][c][j];
                    if (EPI == 1) v = fmaxf(v, 0.f);
                    ot[(wr * 64 + r * 16 + gq * 4 + j) * 132 +
                       wc * (16 * NB) + c * 16 + lo] = v;
                }
    }
    __syncthreads();

    {   // row-major store
        constexpr int TPR = 256 / MT;
        const int r = tid / TPR;
        const int c0 = (tid % TPR) * (MT / 2);
        const int m0s = XORM ? (m0 ^ 128) : m0;
        unsigned short* dst = p.outSM + (size_t)b * p.smB + smOff +
                              (size_t)(m0s + r) * p.ldsm + n0 + c0;
#pragma unroll
        for (int k = 0; k < MT / 16; ++k) {
            u16x8 o;
#pragma unroll
            for (int j = 0; j < 8; ++j) o[j] = f2bf(ot[r * 132 + c0 + 8 * k + j]);
            *(u16x8*)(dst + 8 * k) = o;
        }
    }

    if (CMOUT) {   // column-major store
        const int c = tid >> 1, r0 = (tid & 1) * (MT / 2);
        const float* dv = p.dinv + (size_t)b * Np + m0 + r0;
        unsigned short* dst = p.outCM + (size_t)b * p.cmB +
                              (size_t)(n0 + c) * Np + m0 + r0;
#pragma unroll
        for (int k = 0; k < MT / 16; ++k) {
            u16x8 o;
#pragma unroll
            for (int j = 0; j < 8; ++j) {
                float v = ot[(r0 + 8 * k + j) * 132 + c];
                if (CMOUT == 2) v *= dv[8 * k + j];
                o[j] = f2bf(v);
            }
            *(u16x8*)(dst + 8 * k) = o;
        }
    }

    if (BNSTAT) {
        float* p1 = (float*)(lds + OTB);
        float* p2 = p1 + 256;
        const int col = tid & 127, half = tid >> 7;
        float s = 0.f, s2 = 0.f;
#pragma unroll
        for (int i = 0; i < MT / 2; ++i) {
            float v = ot[(half * (MT / 2) + i) * 132 + col];
            s += v;
            if (BNSTAT == 2) s2 = fmaf(v, v, s2);
        }
        p1[half * 128 + col] = s;
        if (BNSTAT == 2) p2[half * 128 + col] = s2;
        __syncthreads();
        if (tid < 128) {
            float aa = p1[tid] + p1[128 + tid];
            size_t slot = ((size_t)b * gridDim.y + blockIdx.y) * 256 + n0 + tid;
            p.ps[slot] = aa;
            if (BNSTAT == 2) p.ps2[slot] = p2[tid] + p2[128 + tid];
        }
    }
}

// ---------------------------------------------------------------------------
// prep: weight f32->bf16 (544 items) + input transpose (800 items)
// ---------------------------------------------------------------------------
__global__ __launch_bounds__(256) void prep_k(
    const float* __restrict__ x, const float* __restrict__ Wt,
    const float* __restrict__ Wp, const float* __restrict__ Wg,
    const float* __restrict__ W1, const float* __restrict__ W2,
    unsigned short* __restrict__ Wcomb, unsigned short* __restrict__ Wgh,
    unsigned short* __restrict__ W1h, unsigned short* __restrict__ W2h,
    float* __restrict__ out_sm, unsigned short* __restrict__ outh)
{
    __shared__ float tb[64][65];
    int item = blockIdx.x;
    int t = threadIdx.x;
    if (item < 544) {
        size_t e = ((size_t)item * 256 + t) * 4;
        const float* src; unsigned short* dst;
        if (e < 32768)       { src = Wt + e;           dst = Wcomb + e; }
        else if (e < 65536)  { src = Wp + (e - 32768); dst = Wcomb + e; }
        else if (e < 229376) { size_t o = e - 65536;  src = Wg + o; dst = Wgh + o; }
        else if (e < 393216) { size_t o = e - 229376; src = W1 + o; dst = W1h + o; }
        else                 { size_t o = e - 393216; src = W2 + o; dst = W2h + o; }
        float4 v = *(const float4*)src;
        u16x4 t4;
        t4[0] = f2bf(v.x); t4[1] = f2bf(v.y); t4[2] = f2bf(v.z); t4[3] = f2bf(v.w);
        *(u16x4*)dst = t4;
        return;
    }
    int it = item - 544;
    int nx = it % 50, cy = (it / 50) % 4, b = it / 200;
    int c0 = cy * 64, n0 = nx * 64;
    const bool pad = (n0 >= NcT);
    if (!pad) {
        int ci = t >> 2, nb = (t & 3) * 16;
        const float* src = x + ((size_t)b * Cc + c0 + ci) * NcT + n0 + nb;
#pragma unroll
        for (int k = 0; k < 4; ++k) {
            float4 v = *(const float4*)(src + 4 * k);
            tb[ci][nb + 4 * k + 0] = v.x; tb[ci][nb + 4 * k + 1] = v.y;
            tb[ci][nb + 4 * k + 2] = v.z; tb[ci][nb + 4 * k + 3] = v.w;
        }
    }
    __syncthreads();
    int r = t >> 2, cb = (t & 3) * 16;
    size_t off = ((size_t)b * Np + n0 + r) * 256 + c0 + cb;
    float vv[16];
#pragma unroll
    for (int j = 0; j < 16; ++j) vv[j] = pad ? 0.f : tb[cb + j][r];
    float* dst = out_sm + off;
#pragma unroll
    for (int k = 0; k < 4; ++k) {
        float4 v; v.x = vv[4*k]; v.y = vv[4*k+1]; v.z = vv[4*k+2]; v.w = vv[4*k+3];
        *(float4*)(dst + 4 * k) = v;
    }
    u16x8 h1, h2;
#pragma unroll
    for (int j = 0; j < 8; ++j) { h1[j] = f2bf(vv[j]); h2[j] = f2bf(vv[8 + j]); }
    unsigned short* dh = outh + off;
    *(u16x8*)dh = h1;
    *(u16x8*)(dh + 8) = h2;
}

// dinv[b][i] = d>0 ? rsqrt(d) : 0, d = 0.5*sum_q U[b][i][q]*rs[b][q^128]
__global__ __launch_bounds__(256) void dinv_k(
    const unsigned short* __restrict__ U, const float* __restrict__ rp,
    float* __restrict__ dinv)
{
    __shared__ float rsl[256];
    int b = blockIdx.y, tid = threadIdx.x;
    float s = 0.f;
    for (int j = 0; j < 25; ++j) s += rp[((size_t)b * 25 + j) * 256 + tid];
    rsl[tid ^ 128] = s;
    __syncthreads();
    int i = blockIdx.x * 256 + tid;
    if (i < Np) {
        const unsigned short* row = U + ((size_t)b * Np + i) * 256;
        float acc = 0.f;
        for (int q0 = 0; q0 < 256; q0 += 8) {
            u16x8 v = *(const u16x8*)(row + q0);
#pragma unroll
            for (int j = 0; j < 8; ++j) acc = fmaf(bf2f(v[j]), rsl[q0 + j], acc);
        }
        float d = 0.5f * acc;
        dinv[(size_t)b * Np + i] = d > 0.f ? rsqrtf(d) : 0.f;
    }
}

// BN finalize: 16 blocks x 16 channels; 100 partial groups
__global__ __launch_bounds__(256) void bnfin_k(
    const float* __restrict__ ps, const float* __restrict__ ps2,
    const float* __restrict__ gamma, const float* __restrict__ beta,
    float* __restrict__ scale, float* __restrict__ shift)
{
    __shared__ float l1[256], l2[256];
    int t = threadIdx.x;
    int c = blockIdx.x * 16 + (t & 15);
    int gl = t >> 4;
    float a = 0.f, a2 = 0.f;
    for (int g = gl; g < 100; g += 16) {
        a += ps[(size_t)g * 256 + c];
        a2 += ps2[(size_t)g * 256 + c];
    }
    l1[t] = a; l2[t] = a2;
    __syncthreads();
    if (gl == 0) {
#pragma unroll
        for (int j = 1; j < 16; ++j) {
            a += l1[j * 16 + (t & 15)];
            a2 += l2[j * 16 + (t & 15)];
        }
        const float inv = 1.f / (float)(Bc * NcT);
        float mean = a * inv;
        float var = a2 * inv - mean * mean;
        float sc = gamma[c] * rsqrtf(var + EPSc);
        scale[c] = sc;
        shift[c] = beta[c] - mean * sc;
    }
}

// d_out[b][c][n] = transpose(out_sm + BN(o_sm))   (final stage fused)
__global__ __launch_bounds__(256) void xpoutbn_k(
    const float* __restrict__ out_sm, const unsigned short* __restrict__ oin,
    const float* __restrict__ scale, const float* __restrict__ shift,
    float* __restrict__ outp)
{
    __shared__ float tb[64][65];
    __shared__ float lsc[64], lsh[64];
    int b = blockIdx.z, c0 = blockIdx.y * 64, n0 = blockIdx.x * 64;
    int t = threadIdx.x;
    if (t < 64) { lsc[t] = scale[c0 + t]; lsh[t] = shift[c0 + t]; }
    __syncthreads();
    {
        int r = t >> 2, cb = (t & 3) * 16;
        size_t off = ((size_t)b * Np + n0 + r) * 256 + c0 + cb;
#pragma unroll
        for (int k = 0; k < 2; ++k) {
            float4 a0 = *(const float4*)(out_sm + off + 8 * k);
            float4 a1 = *(const float4*)(out_sm + off + 8 * k + 4);
            u16x8 ov = *(const u16x8*)(oin + off + 8 * k);
            tb[r][cb + 8*k + 0] = a0.x + fmaf(bf2f(ov[0]), lsc[cb + 8*k + 0], lsh[cb + 8*k + 0]);
            tb[r][cb + 8*k + 1] = a0.y + fmaf(bf2f(ov[1]), lsc[cb + 8*k + 1], lsh[cb + 8*k + 1]);
            tb[r][cb + 8*k + 2] = a0.z + fmaf(bf2f(ov[2]), lsc[cb + 8*k + 2], lsh[cb + 8*k + 2]);
            tb[r][cb + 8*k + 3] = a0.w + fmaf(bf2f(ov[3]), lsc[cb + 8*k + 3], lsh[cb + 8*k + 3]);
            tb[r][cb + 8*k + 4] = a1.x + fmaf(bf2f(ov[4]), lsc[cb + 8*k + 4], lsh[cb + 8*k + 4]);
            tb[r][cb + 8*k + 5] = a1.y + fmaf(bf2f(ov[5]), lsc[cb + 8*k + 5], lsh[cb + 8*k + 5]);
            tb[r][cb + 8*k + 6] = a1.z + fmaf(bf2f(ov[6]), lsc[cb + 8*k + 6], lsh[cb + 8*k + 6]);
            tb[r][cb + 8*k + 7] = a1.w + fmaf(bf2f(ov[7]), lsc[cb + 8*k + 7], lsh[cb + 8*k + 7]);
        }
    }
    __syncthreads();
    {
        int c = t >> 2, rb = (t & 3) * 16;
        float vv[16];
#pragma unroll
        for (int j = 0; j < 16; ++j) vv[j] = tb[rb + j][c];
        float* dst = outp + ((size_t)b * Cc + c0 + c) * NcT + n0 + rb;
#pragma unroll
        for (int k = 0; k < 4; ++k) {
            float4 v; v.x = vv[4*k]; v.y = vv[4*k+1]; v.z = vv[4*k+2]; v.w = vv[4*k+3];
            *(float4*)(dst + 4 * k) = v;
        }
    }
}

}  // namespace

extern "C" void kernel_launch(void* const* d_in, const int* in_sizes, int n_in,
                              void* d_out, int out_size, void* d_ws, size_t ws_size,
                              hipStream_t stream) {
    const float* x     = (const float*)d_in[0];
    const float* Wt    = (const float*)d_in[1];
    const float* Wp    = (const float*)d_in[2];
    const float* Wg    = (const float*)d_in[3];
    const float* W1    = (const float*)d_in[4];
    const float* W2    = (const float*)d_in[5];
    const float* gamma = (const float*)d_in[6];
    const float* beta  = (const float*)d_in[7];

    char* p = (char*)d_ws;
    auto alloc = [&](size_t bytes) { char* r = p; p += (bytes + 255) & ~(size_t)255; return r; };
    float*          out_sm = (float*)         alloc((size_t)Bc * Np * 256 * 4);
    unsigned short* outh   = (unsigned short*)alloc((size_t)Bc * Np * 256 * 2);
    unsigned short* U_sm   = (unsigned short*)alloc((size_t)Bc * Np * 256 * 2);
    unsigned short* U_cm   = (unsigned short*)alloc((size_t)Bc * 256 * Np * 2);
    unsigned short* g_sm   = (unsigned short*)alloc((size_t)Bc * Np * Pc * 2);
    unsigned short* g_cmd  = (unsigned short*)alloc((size_t)Bc * Pc * Np * 2);
    unsigned short* o_sm   = (unsigned short*)alloc((size_t)Bc * Np * 256 * 2);
    unsigned short* Cpart  = (unsigned short*)alloc((size_t)KSn * Bc * 256 * Pc * 2);
    unsigned short* WMb    = (unsigned short*)alloc((size_t)Bc * Cc * 256 * 2);
    unsigned short* Wcomb  = (unsigned short*)alloc((size_t)Cc * Cc * 2);
    unsigned short* Wgh    = (unsigned short*)alloc((size_t)Sc * Pc * Cc * 2);
    unsigned short* W1h    = (unsigned short*)alloc((size_t)Sc * Cc * Pc * 2);
    unsigned short* W2h    = (unsigned short*)alloc((size_t)Sc * Cc * Pc * 2);
    float*          rp     = (float*)         alloc((size_t)100 * 256 * 4);
    float*          dinv   = (float*)         alloc((size_t)Bc * Np * 4);
    float*          ps     = (float*)         alloc((size_t)100 * 256 * 4);
    float*          ps2    = (float*)         alloc((size_t)100 * 256 * 4);
    float*          scale  = (float*)         alloc(256 * 4);
    float*          shiftb = (float*)         alloc(256 * 4);

    const long NpC = (long)Np * 256;
    dim3 blk(256);

    prep_k<<<1344, blk, 0, stream>>>(x, Wt, Wp, Wg, W1, W2,
                                     Wcomb, Wgh, W1h, W2h, out_sm, outh);

    // U = relu([Wt;Wp] @ x): spatial-major + col-major + col sums
    {
        GP g{};
        g.A = outh; g.lda = 256; g.aB = NpC; g.aSl = 0;
        g.Bw = Wcomb; g.ldb = 256; g.bB = 0; g.bSl = 0;
        g.K = 256; g.nsl = 1;
        g.outSM = U_sm; g.ldsm = 256; g.smB = NpC; g.smSlice = 0;
        g.outCM = U_cm; g.cmB = (long)256 * Np;
        g.ps = rp;
        mgemm<128, 1, 1, false, 1, false, false, false>
            <<<dim3(2, 25, Bc), blk, 0, stream>>>(g);
    }

    dinv_k<<<dim3(13, Bc), blk, 0, stream>>>(U_sm, rp, dinv);

    for (int s = 0; s < Sc; ++s) {
        // g = Wg[s] @ out  (FUSEBN applies previous stage's BN to residual)
        {
            GP g{};
            g.A = outh; g.lda = 256; g.aB = NpC; g.aSl = 0;
            g.Bw = Wgh + (size_t)s * Pc * Cc; g.ldb = 256; g.bB = 0; g.bSl = 0;
            g.K = 256; g.nsl = 1;
            g.outSM = g_sm; g.ldsm = 128; g.smB = (long)Np * 128; g.smSlice = 0;
            g.outCM = g_cmd; g.cmB = (long)Pc * Np;
            g.dinv = dinv;
            g.oin = o_sm; g.bnsc = scale; g.bnsh = shiftb; g.resid = out_sm;
            if (s == 0)
                mgemm<64, 0, 2, false, 0, false, false, false>
                    <<<dim3(1, 50, Bc), blk, 0, stream>>>(g);
            else
                mgemm<64, 0, 2, false, 0, true, false, false>
                    <<<dim3(1, 50, Bc), blk, 0, stream>>>(g);
        }
        // Cpart[ks][b][q^128][p] = partial_i U_cm[q][i] * g_cmd[p][i]
        {
            GP g{};
            g.A = U_cm; g.lda = Np; g.aB = (long)256 * Np; g.aSl = 0;
            g.Bw = g_cmd; g.ldb = Np; g.bB = (long)Pc * Np; g.bSl = 0;
            g.K = Np; g.kchunk = KCH; g.nsl = 1;
            g.outSM = Cpart; g.ldsm = 128; g.smB = (long)256 * Pc;
            g.smSlice = (long)Bc * 256 * Pc;
            mgemm<64, 0, 0, true, 0, false, true, false>
                <<<dim3(1, 4, KSn * Bc), blk, 0, stream>>>(g);
        }
        // WM[b][c][q] = sum_ks sum_p W1[c][p] * Cpart[ks][b][q][p]
        {
            GP g{};
            g.A = W1h + (size_t)s * Cc * Pc; g.lda = 128; g.aB = 0; g.aSl = 0;
            g.Bw = Cpart; g.ldb = 128; g.bB = (long)256 * Pc;
            g.bSl = (long)Bc * 256 * Pc;
            g.K = 128; g.nsl = KSn;
            g.outSM = WMb; g.ldsm = 256; g.smB = (long)Cc * 256; g.smSlice = 0;
            mgemm<64, 0, 0, false, 0, false, false, false>
                <<<dim3(2, 4, Bc), blk, 0, stream>>>(g);
        }
        // o = (U @ WM^T) * 0.5*dinv[m] + g @ W2^T  + BN partial stats
        {
            GP g{};
            g.A = U_sm; g.lda = 256; g.aB = NpC; g.aSl = 0;
            g.Bw = WMb; g.ldb = 256; g.bB = (long)Cc * 256; g.bSl = 0;
            g.K = 256; g.nsl = 1;
            g.A2 = g_sm; g.lda2 = 128; g.aB2 = (long)Np * 128;
            g.B2 = W2h + (size_t)s * Cc * Pc; g.ldb2 = 128; g.bB2 = 0;
            g.K2 = 128;
            g.outSM = o_sm; g.ldsm = 256; g.smB = NpC; g.smSlice = 0;
            g.ps = ps; g.ps2 = ps2;
            g.dinv = dinv;
            mgemm<128, 0, 0, false, 2, false, false, true>
                <<<dim3(2, 25, Bc), blk, 0, stream>>>(g);
        }
        bnfin_k<<<16, blk, 0, stream>>>(ps, ps2, gamma + s * Cc, beta + s * Cc,
                                        scale, shiftb);
    }

    // final: d_out = transpose(out_sm + BN(o_sm))
    xpoutbn_k<<<dim3(49, 4, Bc), blk, 0, stream>>>(out_sm, o_sm, scale, shiftb,
                                                   (float*)d_out);
}